// Round 1
// baseline (896.970 us; speedup 1.0000x reference)
//
#include <hip/hip_runtime.h>

#define D 64

// ---------------------------------------------------------------- h = x copy
__global__ void init_h_kernel(const float4* __restrict__ x4,
                              float4* __restrict__ h4, int n4) {
    int i = blockIdx.x * blockDim.x + threadIdx.x;
    int stride = gridDim.x * blockDim.x;
    for (; i < n4; i += stride) h4[i] = x4[i];
}

// ------------------------------------------- edge scatter: h[dst] += relu(x[src]+e)
// one wave (64 lanes) per edge; lane = feature column
__global__ __launch_bounds__(256)
void edge_kernel(const float* __restrict__ x,
                 const int* __restrict__ ei,   // [2, E] flattened
                 const float* __restrict__ ea, // [E, D]
                 float* __restrict__ h, int E) {
    int lane = threadIdx.x & 63;
    int e = (blockIdx.x * blockDim.x + threadIdx.x) >> 6;
    if (e >= E) return;
    int src = ei[e];
    int dst = ei[E + e];
    float v = x[src * D + lane] + ea[e * D + lane];
    v = fmaxf(v, 0.0f);
    atomicAdd(&h[dst * D + lane], v);
}

// ------------------------------------------------ MLP: out = relu(h W1 + b1) W2 + b2
// one wave per row; lane = output column; weights in LDS
__global__ __launch_bounds__(256)
void mlp_kernel(const float* __restrict__ h,
                const float* __restrict__ W1, const float* __restrict__ b1,
                const float* __restrict__ W2, const float* __restrict__ b2,
                float* __restrict__ out, int N) {
    __shared__ float w1s[D * D];
    __shared__ float w2s[D * D];
    __shared__ float b1s[D];
    __shared__ float b2s[D];
    for (int i = threadIdx.x; i < D * D; i += blockDim.x) {
        w1s[i] = W1[i];
        w2s[i] = W2[i];
    }
    if (threadIdx.x < D) {
        b1s[threadIdx.x] = b1[threadIdx.x];
        b2s[threadIdx.x] = b2[threadIdx.x];
    }
    __syncthreads();

    int lane = threadIdx.x & 63;
    int wave = threadIdx.x >> 6;
    int wavesPerBlock = blockDim.x >> 6;
    int row = blockIdx.x * wavesPerBlock + wave;
    int rstride = gridDim.x * wavesPerBlock;

    for (; row < N; row += rstride) {
        float v = h[row * D + lane];
        float acc = b1s[lane];
#pragma unroll
        for (int k = 0; k < D; ++k) {
            acc = fmaf(__shfl(v, k), w1s[k * D + lane], acc);
        }
        acc = fmaxf(acc, 0.0f);
        float acc2 = b2s[lane];
#pragma unroll
        for (int k = 0; k < D; ++k) {
            acc2 = fmaf(__shfl(acc, k), w2s[k * D + lane], acc2);
        }
        out[row * D + lane] = acc2;
    }
}

extern "C" void kernel_launch(void* const* d_in, const int* in_sizes, int n_in,
                              void* d_out, int out_size, void* d_ws, size_t ws_size,
                              hipStream_t stream) {
    const float* x  = (const float*)d_in[0];
    const int*   ei = (const int*)d_in[1];
    const float* ea = (const float*)d_in[2];
    const float* W1 = (const float*)d_in[3];
    const float* b1 = (const float*)d_in[4];
    const float* W2 = (const float*)d_in[5];
    const float* b2 = (const float*)d_in[6];
    float* out = (float*)d_out;

    int N = in_sizes[0] / D;      // 100000
    int E = in_sizes[1] / 2;      // 1200000

    float* h = (float*)d_ws;      // N*D floats = 25.6 MB scratch

    // 1) h = x
    int n4 = N * D / 4;
    int cblocks = (n4 + 255) / 256;
    hipLaunchKernelGGL(init_h_kernel, dim3(cblocks), dim3(256), 0, stream,
                       (const float4*)x, (float4*)h, n4);

    // 2) scatter edges (4 edges per 256-thread block)
    int eblocks = (E + 3) / 4;
    hipLaunchKernelGGL(edge_kernel, dim3(eblocks), dim3(256), 0, stream,
                       x, ei, ea, h, E);

    // 3) MLP (4 rows per block)
    int mblocks = (N + 3) / 4;
    hipLaunchKernelGGL(mlp_kernel, dim3(mblocks), dim3(256), 0, stream,
                       h, W1, b1, W2, b2, out, N);
}

// Round 2
// 531.991 us; speedup vs baseline: 1.6861x; 1.6861x over previous
//
#include <hip/hip_runtime.h>
#include <hip/hip_fp16.h>

#define D 64

// ---------------------------------------------------------------------------
// Edge scatter: agg[dst] += relu(x[src] + ea)  accumulated in fp16 pairs.
// 32 lanes per edge, each lane handles 2 features -> one pk_add_f16 atomic.
// ---------------------------------------------------------------------------
__global__ __launch_bounds__(256)
void edge_kernel(const float* __restrict__ x,
                 const int* __restrict__ ei,   // [2, E] flattened
                 const float* __restrict__ ea, // [E, D]
                 __half2* __restrict__ agg,    // [N, 32] as half2
                 int E) {
    int t = blockIdx.x * blockDim.x + threadIdx.x;
    int e = t >> 5;           // 32 threads per edge
    if (e >= E) return;
    int sub = t & 31;         // feature pair 0..31

    int src = ei[e];
    int dst = ei[E + e];

    float2 xv = *(const float2*)(x + (size_t)src * D + sub * 2);
    float2 ev = *(const float2*)(ea + (size_t)e * D + sub * 2);
    float v0 = fmaxf(xv.x + ev.x, 0.0f);
    float v1 = fmaxf(xv.y + ev.y, 0.0f);
    __half2 hv = __floats2half2_rn(v0, v1);
    unsafeAtomicAdd(agg + (size_t)dst * 32 + sub, hv);
}

// ---------------------------------------------------------------------------
// Fused h = x + agg, then MLP: out = relu(h W1 + b1) W2 + b2.
// One wave per 2 rows; lane = output column. Weights live in VGPRs
// (64+64 per lane); the k-broadcast uses v_readlane (VALU pipe, no LDS).
// ---------------------------------------------------------------------------
__device__ __forceinline__ float bcast(float v, int k) {
    return __uint_as_float(__builtin_amdgcn_readlane(__float_as_uint(v), k));
}

__global__ __launch_bounds__(256)
void mlp_kernel(const float* __restrict__ x,
                const __half* __restrict__ agg, // [N, D] fp16
                const float* __restrict__ W1, const float* __restrict__ b1,
                const float* __restrict__ W2, const float* __restrict__ b2,
                float* __restrict__ out, int N) {
    const int lane = threadIdx.x & 63;

    float w1[D], w2[D];
#pragma unroll
    for (int k = 0; k < D; ++k) w1[k] = W1[k * D + lane];
#pragma unroll
    for (int k = 0; k < D; ++k) w2[k] = W2[k * D + lane];
    const float bb1 = b1[lane];
    const float bb2 = b2[lane];

    const int wave = blockIdx.x * (blockDim.x >> 6) + (threadIdx.x >> 6);
    const int nwaves = gridDim.x * (blockDim.x >> 6);

    for (int row = wave * 2; row < N; row += nwaves * 2) {
        const int rowB = row + 1;
        const bool hasB = rowB < N;

        float va = x[(size_t)row * D + lane] + __half2float(agg[(size_t)row * D + lane]);
        float vb = hasB ? x[(size_t)rowB * D + lane] + __half2float(agg[(size_t)rowB * D + lane])
                        : 0.0f;

        // ---- layer 1 ----
        float a0 = 0.f, a1 = 0.f, c0 = 0.f, c1 = 0.f;
#pragma unroll
        for (int k = 0; k < D; k += 2) {
            float sa0 = bcast(va, k);
            float sa1 = bcast(va, k + 1);
            float sb0 = bcast(vb, k);
            float sb1 = bcast(vb, k + 1);
            a0 = fmaf(sa0, w1[k],     a0);
            a1 = fmaf(sa1, w1[k + 1], a1);
            c0 = fmaf(sb0, w1[k],     c0);
            c1 = fmaf(sb1, w1[k + 1], c1);
        }
        float ra = fmaxf(a0 + a1 + bb1, 0.0f);
        float rb = fmaxf(c0 + c1 + bb1, 0.0f);

        // ---- layer 2 ----
        a0 = 0.f; a1 = 0.f; c0 = 0.f; c1 = 0.f;
#pragma unroll
        for (int k = 0; k < D; k += 2) {
            float sa0 = bcast(ra, k);
            float sa1 = bcast(ra, k + 1);
            float sb0 = bcast(rb, k);
            float sb1 = bcast(rb, k + 1);
            a0 = fmaf(sa0, w2[k],     a0);
            a1 = fmaf(sa1, w2[k + 1], a1);
            c0 = fmaf(sb0, w2[k],     c0);
            c1 = fmaf(sb1, w2[k + 1], c1);
        }
        out[(size_t)row * D + lane] = a0 + a1 + bb2;
        if (hasB) out[(size_t)rowB * D + lane] = c0 + c1 + bb2;
    }
}

extern "C" void kernel_launch(void* const* d_in, const int* in_sizes, int n_in,
                              void* d_out, int out_size, void* d_ws, size_t ws_size,
                              hipStream_t stream) {
    const float* x  = (const float*)d_in[0];
    const int*   ei = (const int*)d_in[1];
    const float* ea = (const float*)d_in[2];
    const float* W1 = (const float*)d_in[3];
    const float* b1 = (const float*)d_in[4];
    const float* W2 = (const float*)d_in[5];
    const float* b2 = (const float*)d_in[6];
    float* out = (float*)d_out;

    int N = in_sizes[0] / D;      // 100000
    int E = in_sizes[1] / 2;      // 1200000

    __half* agg = (__half*)d_ws;  // [N, D] fp16 = 12.8 MB

    // zero the fp16 accumulator (ws is poisoned before every launch)
    hipMemsetAsync(agg, 0, (size_t)N * D * sizeof(__half), stream);

    // edge scatter: 32 threads/edge -> 8 edges per 256-thread block
    int eblocks = (E + 7) / 8;
    hipLaunchKernelGGL(edge_kernel, dim3(eblocks), dim3(256), 0, stream,
                       x, ei, ea, (__half2*)agg, E);

    // fused add + MLP
    int mblocks = 1024;
    hipLaunchKernelGGL(mlp_kernel, dim3(mblocks), dim3(256), 0, stream,
                       x, agg, W1, b1, W2, b2, out, N);
}